// Round 1
// baseline (27.566 us; speedup 1.0000x reference)
//
#include <hip/hip_runtime.h>
#include <math.h>

// Problem constants (from setup_inputs): B=2, M=N=8192, K=32, C=16, O=16, ncells=27
#define BQ 2
#define MQ 8192
#define NP 8192
#define KN 32
#define CH 16
#define OCH 16
#define NCELL 27
#define EPAD 28   // pad e-dim to 28 so LDS rows are 112B (16B-aligned float4 reads)

// coarse cull: neighbor can contribute only if |qloc-nloc|^2 < (0.1 + 0.05*sqrt(3))^2 = 0.0348207
#define THR2 0.0349f

__global__ __launch_bounds__(256, 4) void convsp_kernel(
    const float* __restrict__ qlocs,
    const float* __restrict__ locs,
    const float* __restrict__ data,
    const int*   __restrict__ neighbors,
    const float* __restrict__ weight,
    const float* __restrict__ bias,
    float* __restrict__ out)
{
    // weight staged in LDS as [o][c][e(pad 28)] -> 28672 B
    __shared__ float wlds[OCH * CH * EPAD];

    const int tid = threadIdx.x;
    for (int idx = tid; idx < OCH * CH * NCELL; idx += 256) {
        int oc = idx / NCELL;
        int e  = idx - oc * NCELL;
        wlds[oc * EPAD + e] = weight[idx];
    }
    if (tid < OCH * CH) wlds[tid * EPAD + NCELL] = 0.0f;  // zero the pad
    __syncthreads();

    const int lane     = tid & 63;
    const int c        = lane & 15;        // channel / output lane within group
    const int grp_base = lane & 48;        // first lane of this 16-lane group
    const int pt       = blockIdx.x * 16 + (tid >> 4);   // query point (b*M+m)
    const int b        = pt >> 13;                        // pt / M (M=8192)

    const float qx = qlocs[pt * 3 + 0];
    const float qy = qlocs[pt * 3 + 1];
    const float qz = qlocs[pt * 3 + 2];

    // --- parallel neighbor scan: lane c owns k=c and k=c+16 ---
    const int nbase = pt * KN;
    int nid0 = neighbors[nbase + c];
    int nid1 = neighbors[nbase + c + 16];

    int g0 = (b * NP + max(nid0, 0)) * 3;
    int g1 = (b * NP + max(nid1, 0)) * 3;
    float l0x = locs[g0], l0y = locs[g0 + 1], l0z = locs[g0 + 2];
    float l1x = locs[g1], l1y = locs[g1 + 1], l1z = locs[g1 + 2];

    float dx0 = qx - l0x, dy0 = qy - l0y, dz0 = qz - l0z;
    float dx1 = qx - l1x, dy1 = qy - l1y, dz1 = qz - l1z;
    bool hit0 = (nid0 >= 0) && (dx0 * dx0 + dy0 * dy0 + dz0 * dz0 < THR2);
    bool hit1 = (nid1 >= 0) && (dx1 * dx1 + dy1 * dy1 + dz1 * dz1 < THR2);

    unsigned long long bl0 = __ballot(hit0);
    unsigned long long bl1 = __ballot(hit1);
    unsigned int mask = (unsigned int)((bl0 >> grp_base) & 0xFFFFull)
                      | ((unsigned int)((bl1 >> grp_base) & 0xFFFFull) << 16);

    float acc[EPAD];
    #pragma unroll
    for (int e = 0; e < EPAD; ++e) acc[e] = 0.0f;

    const bool had = (mask != 0);

    // --- sparse hit loop (group-uniform) ---
    unsigned int mrem = mask;
    while (mrem) {
        int k = __builtin_ctz(mrem);
        mrem &= mrem - 1;
        int src = grp_base + (k & 15);
        bool hi = (k >= 16);

        int   nA = __shfl(nid0, src, 64), nB = __shfl(nid1, src, 64);
        float ax = __shfl(l0x, src, 64),  bx = __shfl(l1x, src, 64);
        float ay = __shfl(l0y, src, 64),  by = __shfl(l1y, src, 64);
        float az = __shfl(l0z, src, 64),  bz = __shfl(l1z, src, 64);

        int   nid = hi ? nB : nA;
        float nx  = hi ? bx : ax;
        float ny  = hi ? by : ay;
        float nz  = hi ? bz : az;

        // per-channel neighbor feature: 64B coalesced within the group
        float ndc = data[(b * NP + nid) * CH + c];

        float dqx = qx - nx, dqy = qy - ny, dqz = qz - nz;
        #pragma unroll
        for (int e = 0; e < NCELL; ++e) {
            const float ox = (float)(e / 9 - 1) * 0.05f;
            const float oy = (float)((e / 3) % 3 - 1) * 0.05f;
            const float oz = (float)(e % 3 - 1) * 0.05f;
            float ex = dqx + ox, ey = dqy + oy, ez = dqz + oz;
            float t = ex * ex + ey * ey + ez * ez + 1e-12f;
            // kv = (1-q)^3 for q<1 else 0  ==  cube(max(0, 1-10*sqrt(t)))
            float u = fmaxf(1.0f - 10.0f * sqrtf(t), 0.0f);
            acc[e] += (u * u * u) * ndc;
        }
    }

    // --- contraction with weights + reduce over c ---
    float r = 0.0f;
    if (had) {
        float v[OCH];
        #pragma unroll
        for (int o = 0; o < OCH; ++o) {
            const float4* w4 = (const float4*)&wlds[(o * CH + c) * EPAD];
            float p = 0.0f;
            #pragma unroll
            for (int j = 0; j < 7; ++j) {
                float4 w = w4[j];
                p += w.x * acc[4 * j + 0] + w.y * acc[4 * j + 1]
                   + w.z * acc[4 * j + 2] + w.w * acc[4 * j + 3];
            }
            v[o] = p;
        }
        // pruned reduce-scatter across the 16-lane group: lane c ends with sum for o=c
        #pragma unroll
        for (int i = 0; i < 4; ++i) {
            int bit = (c >> i) & 1;
            #pragma unroll
            for (int j2 = 0; j2 < (8 >> i); ++j2) {
                float keep = bit ? v[2 * j2 + 1] : v[2 * j2];
                float send = bit ? v[2 * j2]     : v[2 * j2 + 1];
                float recv = __shfl_xor(send, 1 << i, 64);
                v[j2] = keep + recv;
            }
        }
        r = v[0];
    }

    out[pt * OCH + c] = r + bias[c];
}

extern "C" void kernel_launch(void* const* d_in, const int* in_sizes, int n_in,
                              void* d_out, int out_size, void* d_ws, size_t ws_size,
                              hipStream_t stream) {
    const float* qlocs     = (const float*)d_in[0];
    const float* locs      = (const float*)d_in[1];
    const float* data      = (const float*)d_in[2];
    const int*   neighbors = (const int*)d_in[3];
    const float* weight    = (const float*)d_in[4];
    const float* bias      = (const float*)d_in[5];
    float*       out       = (float*)d_out;

    const int BM = in_sizes[0] / 3;   // B*M = 16384
    dim3 grid(BM / 16), block(256);
    hipLaunchKernelGGL(convsp_kernel, grid, block, 0, stream,
                       qlocs, locs, data, neighbors, weight, bias, out);
}

// Round 2
// 24.186 us; speedup vs baseline: 1.1397x; 1.1397x over previous
//
#include <hip/hip_runtime.h>
#include <math.h>

// Problem constants: B=2, M=N=8192, K=32, C=16, O=16, ncells=27
#define NP 8192
#define KN 32
#define CH 16
#define OCH 16
#define NCELL 27
#define EPAD 36   // floats per (o,c) row: 27 real + 5 zero (e=27..31) + 4 dead pad
                  // bank step per c = 36%32=4 -> uniform 4x coverage, no hotspot

// exact cull bound: (0.1 + 0.05*sqrt(3))^2 = 0.0348205; 0.0349 is safely inclusive
#define THR2 0.0349f

__global__ __launch_bounds__(512, 8) void convsp_kernel(
    const float* __restrict__ qlocs,
    const float* __restrict__ locs,
    const float* __restrict__ data,
    const int*   __restrict__ neighbors,
    const float* __restrict__ weight,
    const float* __restrict__ bias,
    float* __restrict__ out)
{
    __shared__ float  wlds[OCH * CH * EPAD];  // 36864 B
    __shared__ float4 offs4[32];              // 512 B cell-offset table (e>=27 -> 0)

    const int tid  = threadIdx.x;
    const int lane = tid & 63;
    const int c    = lane & 15;          // channel
    const int h    = (lane >> 4) & 1;    // e-half: h=0 -> e 0..15, h=1 -> e 16..31
    const int g32  = lane & 32;          // 32-lane group base (2 points per wave)
    const int pt   = blockIdx.x * 16 + (tid >> 5);
    const int b    = pt >> 13;           // pt / M

    // ---- issue independent loads first (hide latency under staging) ----
    const int kk = lane & 31;            // this lane's neighbor slot
    int   nid = neighbors[pt * KN + kk];
    float qx = qlocs[pt * 3 + 0];
    float qy = qlocs[pt * 3 + 1];
    float qz = qlocs[pt * 3 + 2];
    float bi = bias[c];

    // ---- stage weight rows (27 real + zero pad) ----
    for (int idx = tid; idx < OCH * CH * NCELL; idx += 512) {
        int row = idx / NCELL;
        int e   = idx - row * NCELL;
        wlds[row * EPAD + e] = weight[idx];
    }
    for (int idx = tid; idx < OCH * CH * 9; idx += 512) {
        int row = idx / 9;
        int e   = 27 + (idx - row * 9);
        wlds[row * EPAD + e] = 0.0f;     // e = 27..35 zeroed
    }
    if (tid < 32) {
        int e = tid;
        float ox = (e < NCELL) ? (float)(e / 9 - 1) * 0.05f : 0.0f;
        float oy = (e < NCELL) ? (float)((e / 3) % 3 - 1) * 0.05f : 0.0f;
        float oz = (e < NCELL) ? (float)(e % 3 - 1) * 0.05f : 0.0f;
        offs4[tid] = make_float4(ox, oy, oz, 0.0f);
    }

    // ---- gather own neighbor's location (nid has landed by now) ----
    int gaddr = (b * NP + max(nid, 0)) * 3;
    float lx = locs[gaddr], ly = locs[gaddr + 1], lz = locs[gaddr + 2];

    __syncthreads();

    // ---- parallel cull scan: one neighbor per lane ----
    float dx = qx - lx, dy = qy - ly, dz = qz - lz;
    bool hit = (nid >= 0) && (dx * dx + dy * dy + dz * dz < THR2);
    unsigned long long bl = __ballot(hit);
    unsigned int mask = (unsigned int)(bl >> g32);   // this point's 32-bit hit mask

    float acc[16];
    #pragma unroll
    for (int i = 0; i < 16; ++i) acc[i] = 0.0f;

    // opaque pointer: blocks LICM from hoisting 16 loop-invariant ds_read_b128
    // (would need 64 VGPRs -> spill under the 64-reg cap)
    const float4* otab = &offs4[h * 16];

    // ---- sparse hit loop (group-uniform mask) ----
    unsigned int mrem = mask;
    while (mrem) {
        int k = __builtin_ctz(mrem);
        mrem &= mrem - 1;
        int src = g32 + k;

        int   nk = __shfl(nid, src, 64);
        float nx = __shfl(lx,  src, 64);
        float ny = __shfl(ly,  src, 64);
        float nz = __shfl(lz,  src, 64);

        float ndc = data[(b * NP + nk) * CH + c];   // 64B coalesced per point

        float dqx = qx - nx, dqy = qy - ny, dqz = qz - nz;

        const float4* ot = otab;
        asm volatile("" : "+v"(ot));   // keep table reads inside the loop

        #pragma unroll
        for (int i = 0; i < 16; ++i) {
            float4 o4 = ot[i];
            float ex = dqx + o4.x, ey = dqy + o4.y, ez = dqz + o4.z;
            float t = fmaf(ex, ex, fmaf(ey, ey, ez * ez)) + 1e-12f;
            // kv = max(0, 1 - 10*sqrt(t))^3 ; dummy cells (e>=27) hit w==0 rows
            float u = fmaxf(fmaf(-10.0f, __builtin_amdgcn_sqrtf(t), 1.0f), 0.0f);
            acc[i] += (u * u) * (u * ndc);
        }
    }

    // ---- contraction: lane (c,h) dots its e-half against all 16 outputs ----
    float v[16];
    if (mask) {
        #pragma unroll
        for (int o = 0; o < OCH; ++o) {
            const float4* w4 = (const float4*)&wlds[(o * CH + c) * EPAD + h * 16];
            float p = 0.0f;
            #pragma unroll
            for (int j = 0; j < 4; ++j) {
                float4 w = w4[j];
                p += w.x * acc[4 * j + 0] + w.y * acc[4 * j + 1]
                   + w.z * acc[4 * j + 2] + w.w * acc[4 * j + 3];
            }
            v[o] = p;
        }
    } else {
        #pragma unroll
        for (int o = 0; o < OCH; ++o) v[o] = 0.0f;
    }

    // merge the two e-halves (lanes +-16)
    #pragma unroll
    for (int o = 0; o < OCH; ++o) v[o] += __shfl_xor(v[o], 16, 64);

    // pruned reduce-scatter over c: lane c ends with the sum for o=c
    #pragma unroll
    for (int i = 0; i < 4; ++i) {
        int bit = (c >> i) & 1;
        #pragma unroll
        for (int j = 0; j < (8 >> i); ++j) {
            float keep = bit ? v[2 * j + 1] : v[2 * j];
            float send = bit ? v[2 * j]     : v[2 * j + 1];
            float recv = __shfl_xor(send, 1 << i, 64);
            v[j] = keep + recv;
        }
    }

    if (h == 0) out[pt * OCH + c] = v[0] + bi;
}

extern "C" void kernel_launch(void* const* d_in, const int* in_sizes, int n_in,
                              void* d_out, int out_size, void* d_ws, size_t ws_size,
                              hipStream_t stream) {
    const float* qlocs     = (const float*)d_in[0];
    const float* locs      = (const float*)d_in[1];
    const float* data      = (const float*)d_in[2];
    const int*   neighbors = (const int*)d_in[3];
    const float* weight    = (const float*)d_in[4];
    const float* bias      = (const float*)d_in[5];
    float*       out       = (float*)d_out;

    const int BM = in_sizes[0] / 3;   // B*M = 16384
    dim3 grid(BM / 16), block(512);
    hipLaunchKernelGGL(convsp_kernel, grid, block, 0, stream,
                       qlocs, locs, data, neighbors, weight, bias, out);
}

// Round 3
// 21.245 us; speedup vs baseline: 1.2975x; 1.1385x over previous
//
#include <hip/hip_runtime.h>
#include <math.h>

// Problem constants: B=2, M=N=8192, K=32, C=16, O=16, ncells=27
#define NP 8192
#define KN 32
#define CH 16
#define OCH 16
#define NCELL 27
#define EPAD 36   // row stride: 27 real + 9 zeros; 36%32=4 -> good bank spread

// exact cull bound: (0.1 + 0.05*sqrt(3))^2 = 0.0348205; 0.0349 safely inclusive
#define THR2 0.0349f

__global__ __launch_bounds__(1024, 8) void convsp_kernel(
    const float* __restrict__ qlocs,
    const float* __restrict__ locs,
    const float* __restrict__ data,
    const int*   __restrict__ neighbors,
    const float* __restrict__ weight,
    const float* __restrict__ bias,
    float* __restrict__ out)
{
    __shared__ float  wlds[OCH * CH * EPAD];  // 36864 B
    __shared__ float4 offs4[32];              // cell offsets, e>=27 -> 0

    const int tid  = threadIdx.x;
    const int lane = tid & 63;
    const int c    = lane & 15;        // channel
    const int h    = lane >> 4;        // 0..3: e-slice (8 cells each)
    const int pt   = blockIdx.x * 16 + (tid >> 6);   // one wave = one point
    const int b    = pt >> 13;         // pt / M

    // ---- issue independent loads first ----
    int   nid = neighbors[pt * KN + (lane & 31)];   // dup in upper half-wave
    float qx = qlocs[pt * 3 + 0];
    float qy = qlocs[pt * 3 + 1];
    float qz = qlocs[pt * 3 + 2];

    // ---- stage weights: [o][c][e(36)] with e=27..35 zeroed ----
    for (int idx = tid; idx < OCH * CH * NCELL; idx += 1024) {
        int row = idx / NCELL;
        int e   = idx - row * NCELL;
        wlds[row * EPAD + e] = weight[idx];
    }
    for (int idx = tid; idx < OCH * CH * 9; idx += 1024) {
        int row = idx / 9;
        int e   = 27 + (idx - row * 9);
        wlds[row * EPAD + e] = 0.0f;
    }
    if (tid < 32) {
        int e = tid;
        float ox = (e < NCELL) ? (float)(e / 9 - 1) * 0.05f : 0.0f;
        float oy = (e < NCELL) ? (float)((e / 3) % 3 - 1) * 0.05f : 0.0f;
        float oz = (e < NCELL) ? (float)(e % 3 - 1) * 0.05f : 0.0f;
        offs4[tid] = make_float4(ox, oy, oz, 0.0f);
    }

    // ---- gather own neighbor's location (overlaps staging) ----
    int gaddr = (b * NP + max(nid, 0)) * 3;
    float lx = locs[gaddr], ly = locs[gaddr + 1], lz = locs[gaddr + 2];

    __syncthreads();

    // ---- cull scan: lanes 0..31 own k, upper half mirrors; mask wave-uniform ----
    float dx = qx - lx, dy = qy - ly, dz = qz - lz;
    bool hit = (nid >= 0) && (dx * dx + dy * dy + dz * dz < THR2);
    unsigned int mask = (unsigned int)__ballot(hit);   // low32 == high32

    float acc[8];
    #pragma unroll
    for (int i = 0; i < 8; ++i) acc[i] = 0.0f;

    // opaque pointer: stops LICM hoisting 8 float4 table reads (32 VGPRs)
    const float4* otab = &offs4[h * 8];

    // ---- hit loop: wave-uniform, avg ~0.9 iterations ----
    unsigned int mrem = mask;
    while (mrem) {
        int k = __builtin_ctz(mrem);
        mrem &= mrem - 1;

        int   nk = __shfl(nid, k, 64);
        float nx = __shfl(lx,  k, 64);
        float ny = __shfl(ly,  k, 64);
        float nz = __shfl(lz,  k, 64);

        float ndc = data[(b * NP + nk) * CH + c];

        float dqx = qx - nx, dqy = qy - ny, dqz = qz - nz;

        const float4* ot = otab;
        asm volatile("" : "+v"(ot));

        #pragma unroll
        for (int i = 0; i < 8; ++i) {
            float4 o4 = ot[i];
            float ex = dqx + o4.x, ey = dqy + o4.y, ez = dqz + o4.z;
            float t = fmaf(ex, ex, fmaf(ey, ey, ez * ez)) + 1e-12f;
            float u = fmaxf(fmaf(-10.0f, __builtin_amdgcn_sqrtf(t), 1.0f), 0.0f);
            acc[i] += (u * u) * (u * ndc);
        }
    }

    // ---- contraction + reduce; whole wave skips when no hits ----
    float r = 0.0f;
    if (mask) {
        const float* wrow = &wlds[c * EPAD + h * 8];

        // fused stage-0 butterfly: compute o-pair dots, immediately combine
        float vv[8];
        #pragma unroll
        for (int j = 0; j < 8; ++j) {
            const float4* wA = (const float4*)(wrow + (2 * j)     * CH * EPAD);
            const float4* wB = (const float4*)(wrow + (2 * j + 1) * CH * EPAD);
            float4 a0 = wA[0], a1 = wA[1];
            float4 b0 = wB[0], b1 = wB[1];
            float pA = a0.x*acc[0] + a0.y*acc[1] + a0.z*acc[2] + a0.w*acc[3]
                     + a1.x*acc[4] + a1.y*acc[5] + a1.z*acc[6] + a1.w*acc[7];
            float pB = b0.x*acc[0] + b0.y*acc[1] + b0.z*acc[2] + b0.w*acc[3]
                     + b1.x*acc[4] + b1.y*acc[5] + b1.z*acc[6] + b1.w*acc[7];
            int bit = c & 1;
            float keep = bit ? pB : pA;
            float send = bit ? pA : pB;
            vv[j] = keep + __shfl_xor(send, 1, 64);
        }
        // remaining c-bit stages
        #pragma unroll
        for (int i = 1; i < 4; ++i) {
            int bit = (c >> i) & 1;
            #pragma unroll
            for (int j = 0; j < (8 >> i); ++j) {
                float keep = bit ? vv[2 * j + 1] : vv[2 * j];
                float send = bit ? vv[2 * j]     : vv[2 * j + 1];
                vv[j] = keep + __shfl_xor(send, 1 << i, 64);
            }
        }
        // merge the 4 e-slices (h)
        r = vv[0];
        r += __shfl_xor(r, 16, 64);
        r += __shfl_xor(r, 32, 64);
    }

    if (h == 0) out[pt * OCH + c] = r + bias[c];
}

extern "C" void kernel_launch(void* const* d_in, const int* in_sizes, int n_in,
                              void* d_out, int out_size, void* d_ws, size_t ws_size,
                              hipStream_t stream) {
    const float* qlocs     = (const float*)d_in[0];
    const float* locs      = (const float*)d_in[1];
    const float* data      = (const float*)d_in[2];
    const int*   neighbors = (const int*)d_in[3];
    const float* weight    = (const float*)d_in[4];
    const float* bias      = (const float*)d_in[5];
    float*       out       = (float*)d_out;

    const int BM = in_sizes[0] / 3;   // B*M = 16384
    dim3 grid(BM / 16), block(1024);
    hipLaunchKernelGGL(convsp_kernel, grid, block, 0, stream,
                       qlocs, locs, data, neighbors, weight, bias, out);
}

// Round 4
// 20.909 us; speedup vs baseline: 1.3184x; 1.0161x over previous
//
#include <hip/hip_runtime.h>
#include <math.h>

// Problem constants: B=2, M=N=8192, K=32, C=16, O=16, ncells=27
#define NP 8192
#define KN 32
#define CH 16
#define OCH 16
#define NCELL 27
#define EPAD 36   // row stride: 27 real + 9 zeros; 36%32=4 -> good bank spread

// exact cull bound: (0.1 + 0.05*sqrt(3))^2 = 0.0348205; 0.0349 safely inclusive
#define THR2 0.0349f

__global__ __launch_bounds__(512, 6) void convsp_kernel(
    const float* __restrict__ qlocs,
    const float* __restrict__ locs,
    const float* __restrict__ data,
    const int*   __restrict__ neighbors,
    const float* __restrict__ weight,
    const float* __restrict__ bias,
    float* __restrict__ out)
{
    __shared__ float  wlds[OCH * CH * EPAD];  // 36864 B
    __shared__ float4 offs4[32];              // cell offsets, e>=27 -> 0

    const int tid  = threadIdx.x;
    const int lane = tid & 63;
    const int c    = lane & 15;        // channel
    const int h    = lane >> 4;        // 0..3: e-slice (8 cells each)
    const int pt   = blockIdx.x * 8 + (tid >> 6);   // one wave = one point
    const int b    = pt >> 13;         // pt / M

    // ---- issue independent loads first ----
    int   nid = neighbors[pt * KN + (lane & 31)];   // dup in upper half-wave
    float qx = qlocs[pt * 3 + 0];
    float qy = qlocs[pt * 3 + 1];
    float qz = qlocs[pt * 3 + 2];
    float bi = bias[c];

    // ---- stage weights via float4 loads: [o][c][e(36)], e=27..35 zeroed ----
    const float4* w4g = (const float4*)weight;     // 6912 floats = 1728 float4
    for (int idx = tid; idx < (OCH * CH * NCELL) / 4; idx += 512) {
        float4 w = w4g[idx];
        int f = idx * 4;
        int r0 = (f + 0) / NCELL, e0 = (f + 0) - r0 * NCELL;
        int r1 = (f + 1) / NCELL, e1 = (f + 1) - r1 * NCELL;
        int r2 = (f + 2) / NCELL, e2 = (f + 2) - r2 * NCELL;
        int r3 = (f + 3) / NCELL, e3 = (f + 3) - r3 * NCELL;
        wlds[r0 * EPAD + e0] = w.x;
        wlds[r1 * EPAD + e1] = w.y;
        wlds[r2 * EPAD + e2] = w.z;
        wlds[r3 * EPAD + e3] = w.w;
    }
    for (int idx = tid; idx < OCH * CH * 9; idx += 512) {
        int row = idx / 9;
        int e   = 27 + (idx - row * 9);
        wlds[row * EPAD + e] = 0.0f;
    }
    if (tid < 32) {
        int e = tid;
        float ox = (e < NCELL) ? (float)(e / 9 - 1) * 0.05f : 0.0f;
        float oy = (e < NCELL) ? (float)((e / 3) % 3 - 1) * 0.05f : 0.0f;
        float oz = (e < NCELL) ? (float)(e % 3 - 1) * 0.05f : 0.0f;
        offs4[tid] = make_float4(ox, oy, oz, 0.0f);
    }

    // ---- gather own neighbor's location (overlaps staging) ----
    int gaddr = (b * NP + max(nid, 0)) * 3;
    float lx = locs[gaddr], ly = locs[gaddr + 1], lz = locs[gaddr + 2];

    __syncthreads();

    // ---- hoist this lane's 8 cell offsets into registers (24 VGPRs) ----
    float oxr[8], oyr[8], ozr[8];
    #pragma unroll
    for (int i = 0; i < 8; ++i) {
        float4 o4 = offs4[h * 8 + i];
        oxr[i] = o4.x; oyr[i] = o4.y; ozr[i] = o4.z;
    }

    // ---- cull scan: lanes 0..31 own k, upper half mirrors; mask wave-uniform ----
    float dx = qx - lx, dy = qy - ly, dz = qz - lz;
    bool hit = (nid >= 0) && (dx * dx + dy * dy + dz * dz < THR2);
    unsigned int mask = (unsigned int)__ballot(hit);   // low32 == high32

    float acc[8];
    #pragma unroll
    for (int i = 0; i < 8; ++i) acc[i] = 0.0f;

    // ---- hit loop: wave-uniform, avg ~0.9 iterations, pure VALU body ----
    unsigned int mrem = mask;
    while (mrem) {
        int k = __builtin_ctz(mrem);
        mrem &= mrem - 1;

        int   nk = __shfl(nid, k, 64);
        float nx = __shfl(lx,  k, 64);
        float ny = __shfl(ly,  k, 64);
        float nz = __shfl(lz,  k, 64);

        float ndc = data[(b * NP + nk) * CH + c];

        float dqx = qx - nx, dqy = qy - ny, dqz = qz - nz;

        #pragma unroll
        for (int i = 0; i < 8; ++i) {
            float ex = dqx + oxr[i], ey = dqy + oyr[i], ez = dqz + ozr[i];
            float t = fmaf(ex, ex, fmaf(ey, ey, ez * ez)) + 1e-12f;
            float u = fmaxf(fmaf(-10.0f, __builtin_amdgcn_sqrtf(t), 1.0f), 0.0f);
            acc[i] += (u * u) * (u * ndc);
        }
    }

    // ---- contraction + reduce; whole wave skips when no hits ----
    float r = 0.0f;
    if (mask) {
        const float* wrow = &wlds[c * EPAD + h * 8];

        // fused stage-0 butterfly: compute o-pair dots, immediately combine
        float vv[8];
        #pragma unroll
        for (int j = 0; j < 8; ++j) {
            const float4* wA = (const float4*)(wrow + (2 * j)     * CH * EPAD);
            const float4* wB = (const float4*)(wrow + (2 * j + 1) * CH * EPAD);
            float4 a0 = wA[0], a1 = wA[1];
            float4 b0 = wB[0], b1 = wB[1];
            float pA = a0.x*acc[0] + a0.y*acc[1] + a0.z*acc[2] + a0.w*acc[3]
                     + a1.x*acc[4] + a1.y*acc[5] + a1.z*acc[6] + a1.w*acc[7];
            float pB = b0.x*acc[0] + b0.y*acc[1] + b0.z*acc[2] + b0.w*acc[3]
                     + b1.x*acc[4] + b1.y*acc[5] + b1.z*acc[6] + b1.w*acc[7];
            int bit = c & 1;
            float keep = bit ? pB : pA;
            float send = bit ? pA : pB;
            vv[j] = keep + __shfl_xor(send, 1, 64);
        }
        // remaining c-bit stages
        #pragma unroll
        for (int i = 1; i < 4; ++i) {
            int bit = (c >> i) & 1;
            #pragma unroll
            for (int j = 0; j < (8 >> i); ++j) {
                float keep = bit ? vv[2 * j + 1] : vv[2 * j];
                float send = bit ? vv[2 * j]     : vv[2 * j + 1];
                vv[j] = keep + __shfl_xor(send, 1 << i, 64);
            }
        }
        // merge the 4 e-slices (h)
        r = vv[0];
        r += __shfl_xor(r, 16, 64);
        r += __shfl_xor(r, 32, 64);
    }

    if (h == 0) out[pt * OCH + c] = r + bi;
}

extern "C" void kernel_launch(void* const* d_in, const int* in_sizes, int n_in,
                              void* d_out, int out_size, void* d_ws, size_t ws_size,
                              hipStream_t stream) {
    const float* qlocs     = (const float*)d_in[0];
    const float* locs      = (const float*)d_in[1];
    const float* data      = (const float*)d_in[2];
    const int*   neighbors = (const int*)d_in[3];
    const float* weight    = (const float*)d_in[4];
    const float* bias      = (const float*)d_in[5];
    float*       out       = (float*)d_out;

    const int BM = in_sizes[0] / 3;   // B*M = 16384
    dim3 grid(BM / 8), block(512);
    hipLaunchKernelGGL(convsp_kernel, grid, block, 0, stream,
                       qlocs, locs, data, neighbors, weight, bias, out);
}

// Round 5
// 18.617 us; speedup vs baseline: 1.4807x; 1.1231x over previous
//
#include <hip/hip_runtime.h>
#include <math.h>

// Problem constants: B=2, M=N=8192, K=32, C=16, O=16, ncells=27
#define NP 8192
#define KN 32
#define CH 16
#define OCH 16
#define NCELL 27
#define EPAD 36   // row stride: 27 real + 9 zeros; c*36%32 = c*4 -> <=2-way banks

// exact cull bound: (0.1 + 0.05*sqrt(3))^2 = 0.0348205; 0.0349 safely inclusive
#define THR2 0.0349f

__global__ __launch_bounds__(512, 4) void convsp_kernel(
    const float* __restrict__ qlocs,
    const float* __restrict__ locs,
    const float* __restrict__ data,
    const int*   __restrict__ neighbors,
    const float* __restrict__ weight,
    const float* __restrict__ bias,
    float* __restrict__ out)
{
    __shared__ float wlds[OCH * CH * EPAD];   // 36864 B

    const int tid  = threadIdx.x;
    const int lane = tid & 63;
    const int c    = lane & 15;        // channel
    const int h    = lane >> 4;        // 0..3: e-slice AND this lane's cull-point
    const int wv   = tid >> 6;         // wave id in block
    const int pt0  = blockIdx.x * 32 + wv * 4;   // wave owns points pt0..pt0+3
    const int b    = blockIdx.x >> 8;  // 512 blocks, 256 per batch
    const int bN   = b * NP;

    // ---- T14 issue-early: weight loads into registers (write to LDS later) ----
    const float4* w4g = (const float4*)weight;   // 6912 floats = 1728 float4
    float4 wr0 = w4g[tid];
    float4 wr1 = w4g[tid + 512];
    float4 wr2 = w4g[tid + 1024];
    float4 wr3 = (tid < 192) ? w4g[tid + 1536] : make_float4(0.f, 0.f, 0.f, 0.f);

    // own cull point (p == h): query coords + two neighbor slots (k=c, k=c+16)
    const int ptq = pt0 + h;
    const float qx = qlocs[ptq * 3 + 0];
    const float qy = qlocs[ptq * 3 + 1];
    const float qz = qlocs[ptq * 3 + 2];
    const float bi = bias[c];
    const int nid0 = neighbors[ptq * KN + c];
    const int nid1 = neighbors[ptq * KN + 16 + c];
    int g0 = (bN + max(nid0, 0)) * 3;
    int g1 = (bN + max(nid1, 0)) * 3;
    float l0x = locs[g0], l0y = locs[g0 + 1], l0z = locs[g0 + 2];
    float l1x = locs[g1], l1y = locs[g1 + 1], l1z = locs[g1 + 2];

    // ---- zero-fill pad columns e=27..35 (independent LDS writes) ----
    for (int idx = tid; idx < OCH * CH * 9; idx += 512) {
        int row = idx / 9;
        wlds[row * EPAD + 27 + (idx - row * 9)] = 0.0f;
    }

    // ---- this lane's 8 cell offsets, computed arithmetically (no LDS table).
    // cells e>=27 are dummies: finite offsets, but they dot against zero rows.
    float oxr[8], oyr[8], ozr[8];
    #pragma unroll
    for (int i = 0; i < 8; ++i) {
        int e  = h * 8 + i;               // 0..31
        int d9 = (e * 228) >> 11;         // e/9  (valid e<32)
        int d3 = (e * 683) >> 11;         // e/3  (valid e<32)
        oxr[i] = (float)(d9 - 1) * 0.05f;
        oyr[i] = (float)(d3 - 3 * d9 - 1) * 0.05f;
        ozr[i] = (float)(e - 3 * d3 - 1) * 0.05f;
    }

    // ---- cull: lane evaluates its 2 slots for point h ----
    float dx0 = qx - l0x, dy0 = qy - l0y, dz0 = qz - l0z;
    float dx1 = qx - l1x, dy1 = qy - l1y, dz1 = qz - l1z;
    bool hit0 = (nid0 >= 0) && (dx0 * dx0 + dy0 * dy0 + dz0 * dz0 < THR2);
    bool hit1 = (nid1 >= 0) && (dx1 * dx1 + dy1 * dy1 + dz1 * dz1 < THR2);
    unsigned long long bl0 = __ballot(hit0);   // bits p*16+j : point p, k=j
    unsigned long long bl1 = __ballot(hit1);   // bits p*16+j : point p, k=16+j

    float acc[4][8];
    #pragma unroll
    for (int p = 0; p < 4; ++p)
        #pragma unroll
        for (int i = 0; i < 8; ++i) acc[p][i] = 0.0f;

    // ---- per-point hit loops (wave-uniform masks, compile-time acc target) ----
    #pragma unroll
    for (int p = 0; p < 4; ++p) {
        unsigned int mp = (unsigned int)((bl0 >> (p * 16)) & 0xFFFFull)
                        | ((unsigned int)((bl1 >> (p * 16)) & 0xFFFFull) << 16);
        while (mp) {
            int k = __builtin_ctz(mp);
            mp &= mp - 1;
            int  src = p * 16 + (k & 15);
            bool lo  = (k < 16);
            int   nk  = __shfl(lo ? nid0 : nid1, src, 64);
            float dqx = __shfl(lo ? dx0  : dx1,  src, 64);
            float dqy = __shfl(lo ? dy0  : dy1,  src, 64);
            float dqz = __shfl(lo ? dz0  : dz1,  src, 64);

            float ndc = data[(bN + nk) * CH + c];   // 64B line, dup x4 groups

            #pragma unroll
            for (int i = 0; i < 8; ++i) {
                float ex = dqx + oxr[i], ey = dqy + oyr[i], ez = dqz + ozr[i];
                float t  = fmaf(ex, ex, fmaf(ey, ey, ez * ez)) + 1e-12f;
                float u  = fmaxf(fmaf(-10.0f, __builtin_amdgcn_sqrtf(t), 1.0f), 0.0f);
                acc[p][i] += (u * u) * (u * ndc);
            }
        }
    }

    // ---- T14 write-late: stage weights to LDS (padded rows), then barrier ----
    #pragma unroll
    for (int j = 0; j < 4; ++j) {
        if (j < 3 || tid < 192) {
            float4 w = (j == 0) ? wr0 : (j == 1) ? wr1 : (j == 2) ? wr2 : wr3;
            int f  = (tid + j * 512) * 4;
            int r0 = (f + 0) / NCELL, e0 = (f + 0) - r0 * NCELL;
            int r1 = (f + 1) / NCELL, e1 = (f + 1) - r1 * NCELL;
            int r2 = (f + 2) / NCELL, e2 = (f + 2) - r2 * NCELL;
            int r3 = (f + 3) / NCELL, e3 = (f + 3) - r3 * NCELL;
            wlds[r0 * EPAD + e0] = w.x;
            wlds[r1 * EPAD + e1] = w.y;
            wlds[r2 * EPAD + e2] = w.z;
            wlds[r3 * EPAD + e3] = w.w;
        }
    }
    __syncthreads();

    // ---- contraction: weight reads shared across the wave's 4 points ----
    float r0s = 0.f, r1s = 0.f, r2s = 0.f, r3s = 0.f;
    if (bl0 | bl1) {
        const float* wrow = &wlds[c * EPAD + h * 8];
        const int bit0 = c & 1;
        float vv[4][8];
        #pragma unroll
        for (int j = 0; j < 8; ++j) {
            const float4* wA = (const float4*)(wrow + (2 * j)     * CH * EPAD);
            const float4* wB = (const float4*)(wrow + (2 * j + 1) * CH * EPAD);
            float4 a0 = wA[0], a1 = wA[1];
            float4 b0 = wB[0], b1 = wB[1];
            #pragma unroll
            for (int p = 0; p < 4; ++p) {
                float pA = a0.x*acc[p][0] + a0.y*acc[p][1] + a0.z*acc[p][2] + a0.w*acc[p][3]
                         + a1.x*acc[p][4] + a1.y*acc[p][5] + a1.z*acc[p][6] + a1.w*acc[p][7];
                float pB = b0.x*acc[p][0] + b0.y*acc[p][1] + b0.z*acc[p][2] + b0.w*acc[p][3]
                         + b1.x*acc[p][4] + b1.y*acc[p][5] + b1.z*acc[p][6] + b1.w*acc[p][7];
                float keep = bit0 ? pB : pA;
                float send = bit0 ? pA : pB;
                vv[p][j] = keep + __shfl_xor(send, 1, 64);
            }
        }
        #pragma unroll
        for (int i = 1; i < 4; ++i) {
            int bit = (c >> i) & 1;
            #pragma unroll
            for (int p = 0; p < 4; ++p) {
                #pragma unroll
                for (int j = 0; j < (8 >> i); ++j) {
                    float keep = bit ? vv[p][2 * j + 1] : vv[p][2 * j];
                    float send = bit ? vv[p][2 * j]     : vv[p][2 * j + 1];
                    vv[p][j] = keep + __shfl_xor(send, 1 << i, 64);
                }
            }
        }
        // merge the 4 e-slices (h groups) per point
        r0s = vv[0][0]; r0s += __shfl_xor(r0s, 16, 64); r0s += __shfl_xor(r0s, 32, 64);
        r1s = vv[1][0]; r1s += __shfl_xor(r1s, 16, 64); r1s += __shfl_xor(r1s, 32, 64);
        r2s = vv[2][0]; r2s += __shfl_xor(r2s, 16, 64); r2s += __shfl_xor(r2s, 32, 64);
        r3s = vv[3][0]; r3s += __shfl_xor(r3s, 16, 64); r3s += __shfl_xor(r3s, 32, 64);
    }

    // lane (c,h) writes point pt0+h, channel o=c  ->  out[pt0*16 + lane], 256B coalesced
    float rw = r0s;
    if (h == 1) rw = r1s;
    if (h == 2) rw = r2s;
    if (h == 3) rw = r3s;
    out[pt0 * CH + lane] = rw + bi;
}

extern "C" void kernel_launch(void* const* d_in, const int* in_sizes, int n_in,
                              void* d_out, int out_size, void* d_ws, size_t ws_size,
                              hipStream_t stream) {
    const float* qlocs     = (const float*)d_in[0];
    const float* locs      = (const float*)d_in[1];
    const float* data      = (const float*)d_in[2];
    const int*   neighbors = (const int*)d_in[3];
    const float* weight    = (const float*)d_in[4];
    const float* bias      = (const float*)d_in[5];
    float*       out       = (float*)d_out;

    const int BM = in_sizes[0] / 3;   // B*M = 16384
    dim3 grid(BM / 32), block(512);
    hipLaunchKernelGGL(convsp_kernel, grid, block, 0, stream,
                       qlocs, locs, data, neighbors, weight, bias, out);
}

// Round 6
// 17.723 us; speedup vs baseline: 1.5553x; 1.0504x over previous
//
#include <hip/hip_runtime.h>
#include <math.h>

// Problem constants: B=2, M=N=8192, K=32, C=16, O=16, ncells=27
#define NP 8192
#define KN 32
#define CH 16
#define OCH 16
#define NCELL 27
#define EPAD 36   // row stride: 27 real + 9 zeros; c*36%32 = c*4 -> <=2-way banks

// exact cull bound: (0.1 + 0.05*sqrt(3))^2 = 0.0348205; 0.0349 safely inclusive
#define THR2 0.0349f

__device__ __forceinline__ float rlf(float x, int l) {
    return __int_as_float(__builtin_amdgcn_readlane(__float_as_int(x), l));
}
// VALU cross-lane: DPP quad_perm / row_ror (1-cyc, no DS pipe, no lgkmcnt)
__device__ __forceinline__ float dpp_xor1(float x) {   // lane ^ 1
    return __int_as_float(__builtin_amdgcn_mov_dpp(__float_as_int(x), 0xB1, 0xF, 0xF, true));
}
__device__ __forceinline__ float dpp_xor2(float x) {   // lane ^ 2
    return __int_as_float(__builtin_amdgcn_mov_dpp(__float_as_int(x), 0x4E, 0xF, 0xF, true));
}
__device__ __forceinline__ float dpp_xor8(float x) {   // lane ^ 8 (row_ror:8 on 16-row)
    return __int_as_float(__builtin_amdgcn_mov_dpp(__float_as_int(x), 0x128, 0xF, 0xF, true));
}
// x + x[lane^16] / x + x[lane^32] via gfx950 permlane swaps (VALU):
// with both operands = x, sum of the two outputs = x + partner on every lane.
__device__ __forceinline__ float fold16(float x) {
#if __has_builtin(__builtin_amdgcn_permlane16_swap)
    typedef unsigned uv2 __attribute__((ext_vector_type(2)));
    uv2 rr = __builtin_amdgcn_permlane16_swap(__float_as_uint(x), __float_as_uint(x), false, false);
    return __uint_as_float(rr[0]) + __uint_as_float(rr[1]);
#else
    return x + __shfl_xor(x, 16, 64);
#endif
}
__device__ __forceinline__ float fold32(float x) {
#if __has_builtin(__builtin_amdgcn_permlane32_swap)
    typedef unsigned uv2 __attribute__((ext_vector_type(2)));
    uv2 rr = __builtin_amdgcn_permlane32_swap(__float_as_uint(x), __float_as_uint(x), false, false);
    return __uint_as_float(rr[0]) + __uint_as_float(rr[1]);
#else
    return x + __shfl_xor(x, 32, 64);
#endif
}

__global__ __launch_bounds__(512, 4) void convsp_kernel(
    const float* __restrict__ qlocs,
    const float* __restrict__ locs,
    const float* __restrict__ data,
    const int*   __restrict__ neighbors,
    const float* __restrict__ weight,
    const float* __restrict__ bias,
    float* __restrict__ out)
{
    __shared__ float wlds[OCH * CH * EPAD];   // 36864 B

    const int tid  = threadIdx.x;
    const int lane = tid & 63;
    const int c    = lane & 15;        // channel
    const int h    = lane >> 4;        // 0..3: e-slice AND this lane's cull-point
    const int wv   = tid >> 6;         // wave id in block
    const int pt0  = blockIdx.x * 32 + wv * 4;   // wave owns points pt0..pt0+3
    const int b    = blockIdx.x >> 8;  // 512 blocks, 256 per batch
    const int bN   = b * NP;

    // ---- T14 issue-early: weight loads into registers (write to LDS later) ----
    const float4* w4g = (const float4*)weight;   // 6912 floats = 1728 float4
    float4 wr0 = w4g[tid];
    float4 wr1 = w4g[tid + 512];
    float4 wr2 = w4g[tid + 1024];
    float4 wr3 = (tid < 192) ? w4g[tid + 1536] : make_float4(0.f, 0.f, 0.f, 0.f);

    // own cull point (p == h): query coords + two neighbor slots (k=c, k=c+16)
    const int ptq = pt0 + h;
    const float qx = qlocs[ptq * 3 + 0];
    const float qy = qlocs[ptq * 3 + 1];
    const float qz = qlocs[ptq * 3 + 2];
    const float bi = bias[c];
    const int nid0 = neighbors[ptq * KN + c];
    const int nid1 = neighbors[ptq * KN + 16 + c];
    int g0 = (bN + max(nid0, 0)) * 3;
    int g1 = (bN + max(nid1, 0)) * 3;
    float l0x = locs[g0], l0y = locs[g0 + 1], l0z = locs[g0 + 2];
    float l1x = locs[g1], l1y = locs[g1 + 1], l1z = locs[g1 + 2];

    // ---- zero-fill pad columns e=27..35 (independent LDS writes) ----
    for (int idx = tid; idx < OCH * CH * 9; idx += 512) {
        int row = idx / 9;
        wlds[row * EPAD + 27 + (idx - row * 9)] = 0.0f;
    }

    // ---- this lane's 8 cell offsets (arithmetic, no LDS table) ----
    float oxr[8], oyr[8], ozr[8];
    #pragma unroll
    for (int i = 0; i < 8; ++i) {
        int e  = h * 8 + i;               // 0..31
        int d9 = (e * 228) >> 11;         // e/9  (valid e<32)
        int d3 = (e * 683) >> 11;         // e/3  (valid e<32)
        oxr[i] = (float)(d9 - 1) * 0.05f;
        oyr[i] = (float)(d3 - 3 * d9 - 1) * 0.05f;
        ozr[i] = (float)(e - 3 * d3 - 1) * 0.05f;
    }

    // ---- cull: lane evaluates its 2 slots for point h ----
    float dx0 = qx - l0x, dy0 = qy - l0y, dz0 = qz - l0z;
    float dx1 = qx - l1x, dy1 = qy - l1y, dz1 = qz - l1z;
    bool hit0 = (nid0 >= 0) && (dx0 * dx0 + dy0 * dy0 + dz0 * dz0 < THR2);
    bool hit1 = (nid1 >= 0) && (dx1 * dx1 + dy1 * dy1 + dz1 * dz1 < THR2);
    unsigned long long bl0 = __ballot(hit0);   // bits p*16+j : point p, slot j
    unsigned long long bl1 = __ballot(hit1);   // bits p*16+j : point p, slot 16+j

    float acc[4][8];
    #pragma unroll
    for (int p = 0; p < 4; ++p)
        #pragma unroll
        for (int i = 0; i < 8; ++i) acc[p][i] = 0.0f;

    // ---- per-point hit loops: scalar control, readlane broadcast (no DS),
    //      1-deep pipelined data gather ----
    #pragma unroll
    for (int p = 0; p < 4; ++p) {
        unsigned int mp = (unsigned int)((bl0 >> (p * 16)) & 0xFFFFull)
                        | ((unsigned int)((bl1 >> (p * 16)) & 0xFFFFull) << 16);

        auto FETCH = [&](int k, int& nk, float& ax, float& ay, float& az) {
            int src = p * 16 + (k & 15);
            if (k < 16) {
                nk = __builtin_amdgcn_readlane(nid0, src);
                ax = rlf(dx0, src); ay = rlf(dy0, src); az = rlf(dz0, src);
            } else {
                nk = __builtin_amdgcn_readlane(nid1, src);
                ax = rlf(dx1, src); ay = rlf(dy1, src); az = rlf(dz1, src);
            }
        };
        auto ACCUM = [&](float (&a)[8], float dqx, float dqy, float dqz, float ndc) {
            #pragma unroll
            for (int i = 0; i < 8; ++i) {
                float ex = dqx + oxr[i], ey = dqy + oyr[i], ez = dqz + ozr[i];
                float t  = fmaf(ex, ex, fmaf(ey, ey, ez * ez)) + 1e-12f;
                float u  = fmaxf(fmaf(-10.0f, __builtin_amdgcn_sqrtf(t), 1.0f), 0.0f);
                a[i] += (u * u) * (u * ndc);
            }
        };

        if (mp) {
            int k = __builtin_ctz(mp); mp &= mp - 1;
            int nk; float dqx, dqy, dqz;
            FETCH(k, nk, dqx, dqy, dqz);
            float ndc = data[(bN + nk) * CH + c];
            while (mp) {
                int k2 = __builtin_ctz(mp); mp &= mp - 1;
                int nk2; float dqx2, dqy2, dqz2;
                FETCH(k2, nk2, dqx2, dqy2, dqz2);
                float ndc2 = data[(bN + nk2) * CH + c];   // in flight during ACCUM
                ACCUM(acc[p], dqx, dqy, dqz, ndc);
                dqx = dqx2; dqy = dqy2; dqz = dqz2; ndc = ndc2;
            }
            ACCUM(acc[p], dqx, dqy, dqz, ndc);
        }
    }

    // ---- T14 write-late: stage weights to LDS (padded rows), then barrier ----
    #pragma unroll
    for (int j = 0; j < 4; ++j) {
        if (j < 3 || tid < 192) {
            float4 w = (j == 0) ? wr0 : (j == 1) ? wr1 : (j == 2) ? wr2 : wr3;
            int f  = (tid + j * 512) * 4;
            int r0 = (f + 0) / NCELL, e0 = (f + 0) - r0 * NCELL;
            int r1 = (f + 1) / NCELL, e1 = (f + 1) - r1 * NCELL;
            int r2 = (f + 2) / NCELL, e2 = (f + 2) - r2 * NCELL;
            int r3 = (f + 3) / NCELL, e3 = (f + 3) - r3 * NCELL;
            wlds[r0 * EPAD + e0] = w.x;
            wlds[r1 * EPAD + e1] = w.y;
            wlds[r2 * EPAD + e2] = w.z;
            wlds[r3 * EPAD + e3] = w.w;
        }
    }
    __syncthreads();

    // ---- contraction: weight reads shared across the wave's 4 points;
    //      butterfly on VALU (DPP/permlane) except xor4 ----
    float r0s = 0.f, r1s = 0.f, r2s = 0.f, r3s = 0.f;
    if (bl0 | bl1) {
        const float* wrow = &wlds[c * EPAD + h * 8];
        const int bit0 = c & 1;
        float vv[4][8];
        #pragma unroll
        for (int j = 0; j < 8; ++j) {
            const float4* wA = (const float4*)(wrow + (2 * j)     * CH * EPAD);
            const float4* wB = (const float4*)(wrow + (2 * j + 1) * CH * EPAD);
            float4 a0 = wA[0], a1 = wA[1];
            float4 b0 = wB[0], b1 = wB[1];
            #pragma unroll
            for (int p = 0; p < 4; ++p) {
                float pA = a0.x*acc[p][0] + a0.y*acc[p][1] + a0.z*acc[p][2] + a0.w*acc[p][3]
                         + a1.x*acc[p][4] + a1.y*acc[p][5] + a1.z*acc[p][6] + a1.w*acc[p][7];
                float pB = b0.x*acc[p][0] + b0.y*acc[p][1] + b0.z*acc[p][2] + b0.w*acc[p][3]
                         + b1.x*acc[p][4] + b1.y*acc[p][5] + b1.z*acc[p][6] + b1.w*acc[p][7];
                float keep = bit0 ? pB : pA;
                float send = bit0 ? pA : pB;
                vv[p][j] = keep + dpp_xor1(send);
            }
        }
        // stage 1: xor2 (DPP)
        {
            const int bit = (c >> 1) & 1;
            #pragma unroll
            for (int p = 0; p < 4; ++p)
                #pragma unroll
                for (int j = 0; j < 4; ++j) {
                    float keep = bit ? vv[p][2 * j + 1] : vv[p][2 * j];
                    float send = bit ? vv[p][2 * j]     : vv[p][2 * j + 1];
                    vv[p][j] = keep + dpp_xor2(send);
                }
        }
        // stage 2: xor4 (DS swizzle — no DPP pattern for lane^4)
        {
            const int bit = (c >> 2) & 1;
            #pragma unroll
            for (int p = 0; p < 4; ++p)
                #pragma unroll
                for (int j = 0; j < 2; ++j) {
                    float keep = bit ? vv[p][2 * j + 1] : vv[p][2 * j];
                    float send = bit ? vv[p][2 * j]     : vv[p][2 * j + 1];
                    vv[p][j] = keep + __shfl_xor(send, 4, 64);
                }
        }
        // stage 3: xor8 (DPP row_ror:8)
        {
            const int bit = (c >> 3) & 1;
            #pragma unroll
            for (int p = 0; p < 4; ++p) {
                float keep = bit ? vv[p][1] : vv[p][0];
                float send = bit ? vv[p][0] : vv[p][1];
                vv[p][0] = keep + dpp_xor8(send);
            }
        }
        // merge the 4 e-slices (h groups) per point: xor16, xor32 on VALU
        r0s = fold32(fold16(vv[0][0]));
        r1s = fold32(fold16(vv[1][0]));
        r2s = fold32(fold16(vv[2][0]));
        r3s = fold32(fold16(vv[3][0]));
    }

    // lane (c,h) writes point pt0+h, channel o=c -> out[pt0*16 + lane], 256B coalesced
    float rw = r0s;
    if (h == 1) rw = r1s;
    if (h == 2) rw = r2s;
    if (h == 3) rw = r3s;
    out[pt0 * CH + lane] = rw + bi;
}

extern "C" void kernel_launch(void* const* d_in, const int* in_sizes, int n_in,
                              void* d_out, int out_size, void* d_ws, size_t ws_size,
                              hipStream_t stream) {
    const float* qlocs     = (const float*)d_in[0];
    const float* locs      = (const float*)d_in[1];
    const float* data      = (const float*)d_in[2];
    const int*   neighbors = (const int*)d_in[3];
    const float* weight    = (const float*)d_in[4];
    const float* bias      = (const float*)d_in[5];
    float*       out       = (float*)d_out;

    const int BM = in_sizes[0] / 3;   // B*M = 16384
    dim3 grid(BM / 32), block(512);
    hipLaunchKernelGGL(convsp_kernel, grid, block, 0, stream,
                       qlocs, locs, data, neighbors, weight, bias, out);
}